// Round 12
// baseline (6499.908 us; speedup 1.0000x reference)
//
#include <hip/hip_runtime.h>
#include <stdint.h>

#define S_ 2048

typedef short s16x8 __attribute__((ext_vector_type(8)));

__device__ __forceinline__ float bf2f(ushort u) {
    union { uint32_t u; float f; } v; v.u = ((uint32_t)u) << 16; return v.f;
}
__device__ __forceinline__ ushort f2bf(float f) {
    union { float f; uint32_t u; } v; v.f = f;
    uint32_t r = v.u + 0x7fffu + ((v.u >> 16) & 1u);
    return (ushort)(r >> 16);
}

// ---------- naive QKV projection: one thread per output element ----------
// All inputs fp32 (R11: W-as-bf16 => NaN => W is fp32; R4 probe: X fp32).
// C[m,n] = sum_k X[m,k] * W[k,n] + b[n];  z in {0,1,2} -> (Q*0.125, K, V)
// out layout [b,h,s,d] bf16: out[((b*16+h)*2048+s)*64+d], h=n>>6, d=n&63
__global__ void qkv_naive(const float* __restrict__ X,
                          const float* __restrict__ W0, const float* __restrict__ W1,
                          const float* __restrict__ W2,
                          const float* __restrict__ b0, const float* __restrict__ b1,
                          const float* __restrict__ b2,
                          ushort* __restrict__ o0, ushort* __restrict__ o1,
                          ushort* __restrict__ o2) {
    const int z = blockIdx.z;
    const float* W  = (z == 0) ? W0 : (z == 1) ? W1 : W2;
    const float* bi = (z == 0) ? b0 : (z == 1) ? b1 : b2;
    ushort* out     = (z == 0) ? o0 : (z == 1) ? o1 : o2;
    const float sc  = (z == 0) ? 0.125f : 1.0f;

    const int n = blockIdx.x * 64 + threadIdx.x;      // output column (coalesced)
    const int m = blockIdx.y * 4 + threadIdx.y;       // output row = b*2048+s
    const float* Xr = X + (size_t)m * 1024;
    float acc = 0.f;
    for (int k = 0; k < 1024; k += 4) {
        acc += Xr[k]     * W[(size_t)k * 1024 + n];
        acc += Xr[k + 1] * W[(size_t)(k + 1) * 1024 + n];
        acc += Xr[k + 2] * W[(size_t)(k + 2) * 1024 + n];
        acc += Xr[k + 3] * W[(size_t)(k + 3) * 1024 + n];
    }
    const float v = (acc + bi[n]) * sc;
    const int b_ = m >> 11, s = m & 2047, h = n >> 6, d = n & 63;
    out[((size_t)(b_ * 16 + h) * 2048 + s) * 64 + d] = f2bf(v);
}

// ---------- naive output projection -> FP32 output ----------
// R12 fix: d_out is an FP32 buffer (reference dtype float32). Writing bf16
// was the 5-pipeline-invariant 0.114 bug: fp32 read of packed bf16 pairs
// decodes to out[2j+1] => decorrelation + bias-miscancel, exactly as observed.
__global__ void out_naive(const ushort* __restrict__ ctx, const float* __restrict__ W,
                          const float* __restrict__ bi, float* __restrict__ out) {
    const int n = blockIdx.x * 64 + threadIdx.x;
    const int m = blockIdx.y * 4 + threadIdx.y;
    const ushort* Ar = ctx + (size_t)m * 1024;
    float acc = 0.f;
    for (int k = 0; k < 1024; k += 4) {
        acc += bf2f(Ar[k])     * W[(size_t)k * 1024 + n];
        acc += bf2f(Ar[k + 1]) * W[(size_t)(k + 1) * 1024 + n];
        acc += bf2f(Ar[k + 2]) * W[(size_t)(k + 2) * 1024 + n];
        acc += bf2f(Ar[k + 3]) * W[(size_t)(k + 3) * 1024 + n];
    }
    out[(size_t)m * 1024 + n] = acc + bi[n];
}

// ---------- VALU flash attention (audited; unchanged) ----------
// grid (S/64, B*H), block 64. One thread per q-row. Q pre-scaled by 1/8.
__global__ void __launch_bounds__(64, 1)
attn_valu(const ushort* __restrict__ q_ws, const ushort* __restrict__ k_ws,
          const ushort* __restrict__ v_ws, ushort* __restrict__ ctx) {
    const int lane = threadIdx.x;
    const int bh = blockIdx.y;
    const int q = blockIdx.x * 64 + lane;

    const ushort* Qr = q_ws + ((size_t)bh * S_ + q) * 64;
    float qr[64];
#pragma unroll
    for (int dc = 0; dc < 8; dc++) {
        s16x8 v8 = *(const s16x8*)(Qr + dc * 8);
#pragma unroll
        for (int j = 0; j < 8; j++) qr[dc * 8 + j] = bf2f((ushort)v8[j]);
    }

    float o[64];
#pragma unroll
    for (int d = 0; d < 64; d++) o[d] = 0.f;
    float m = -1e30f, l = 0.f;

    const ushort* Kb = k_ws + (size_t)bh * S_ * 64;
    const ushort* Vb = v_ws + (size_t)bh * S_ * 64;

    for (int k = 0; k < S_; k++) {
        const ushort* Kr = Kb + (size_t)k * 64;
        float dot = 0.f;
#pragma unroll
        for (int dc = 0; dc < 8; dc++) {
            s16x8 v8 = *(const s16x8*)(Kr + dc * 8);
#pragma unroll
            for (int j = 0; j < 8; j++) dot += qr[dc * 8 + j] * bf2f((ushort)v8[j]);
        }
        if (dot > m) {
            float corr = __expf(m - dot);
            m = dot;
            l *= corr;
#pragma unroll
            for (int d = 0; d < 64; d++) o[d] *= corr;
        }
        float p = __expf(dot - m);
        l += p;
        const ushort* Vr = Vb + (size_t)k * 64;
#pragma unroll
        for (int dc = 0; dc < 8; dc++) {
            s16x8 v8 = *(const s16x8*)(Vr + dc * 8);
#pragma unroll
            for (int j = 0; j < 8; j++)
                o[dc * 8 + j] += p * bf2f((ushort)v8[j]);
        }
    }

    const int b_ = bh >> 4, h = bh & 15;
    ushort* Or = ctx + ((size_t)(b_ * 2048 + q)) * 1024 + h * 64;
#pragma unroll
    for (int d = 0; d < 64; d++) Or[d] = f2bf(o[d] / l);
}

extern "C" void kernel_launch(void* const* d_in, const int* in_sizes, int n_in,
                              void* d_out, int out_size, void* d_ws, size_t ws_size,
                              hipStream_t stream) {
    // Documented dict order; all inputs fp32; OUTPUT fp32.
    const float* X  = (const float*)d_in[0];
    const float* Wq = (const float*)d_in[1];
    const float* bq = (const float*)d_in[2];
    const float* Wk = (const float*)d_in[3];
    const float* bk = (const float*)d_in[4];
    const float* Wv = (const float*)d_in[5];
    const float* bv = (const float*)d_in[6];
    const float* Wo = (const float*)d_in[7];
    const float* bo = (const float*)d_in[8];
    float* out = (float*)d_out;

    // ws: qws@0 (8 MiB), kws@8M, vws@16M, ctx@24M = 32 MiB bf16 buffers.
    char* ws = (char*)d_ws;
    ushort* qws = (ushort*)(ws);
    ushort* kws = (ushort*)(ws + ((size_t)8 << 20));
    ushort* vws = (ushort*)(ws + ((size_t)16 << 20));
    ushort* ctx = (ushort*)(ws + ((size_t)24 << 20));

    qkv_naive<<<dim3(16, 1024, 3), dim3(64, 4), 0, stream>>>(
        X, Wq, Wk, Wv, bq, bk, bv, qws, kws, vws);

    attn_valu<<<dim3(S_ / 64, 32), 64, 0, stream>>>(qws, kws, vws, ctx);

    out_naive<<<dim3(16, 1024), dim3(64, 4), 0, stream>>>(ctx, Wo, bo, out);
}

// Round 13
// 278.959 us; speedup vs baseline: 23.3006x; 23.3006x over previous
//
#include <hip/hip_runtime.h>
#include <stdint.h>

#define S_ 2048
#define H_ 16

typedef short s16x8 __attribute__((ext_vector_type(8)));
typedef float f32x4 __attribute__((ext_vector_type(4)));

__device__ __forceinline__ float bf2f(ushort u) {
    union { uint32_t u; float f; } v; v.u = ((uint32_t)u) << 16; return v.f;
}
__device__ __forceinline__ ushort f2bf(float f) {
    union { float f; uint32_t u; } v; v.f = f;
    uint32_t r = v.u + 0x7fffu + ((v.u >> 16) & 1u);
    return (ushort)(r >> 16);
}
template <bool AF32>
__device__ __forceinline__ s16x8 load8(const void* base, size_t e) {
    if (AF32) {
        const float* p = (const float*)base + e;
        float4 x = *(const float4*)p;
        float4 y = *(const float4*)(p + 4);
        s16x8 r;
        r[0] = (short)f2bf(x.x); r[1] = (short)f2bf(x.y);
        r[2] = (short)f2bf(x.z); r[3] = (short)f2bf(x.w);
        r[4] = (short)f2bf(y.x); r[5] = (short)f2bf(y.y);
        r[6] = (short)f2bf(y.z); r[7] = (short)f2bf(y.w);
        return r;
    }
    return *(const s16x8*)((const ushort*)base + e);
}

// ---- weight prep: dst[n*1024+k] = bf16(src[k*1024+n]) ----
__global__ void transpose_k(const float* __restrict__ src, ushort* __restrict__ dst) {
    __shared__ ushort t[32][33];
    int bx = blockIdx.x * 32, by = blockIdx.y * 32;
    int x = threadIdx.x;
    for (int y = threadIdx.y; y < 32; y += 8)
        t[y][x] = f2bf(src[(size_t)(by + y) * 1024 + bx + x]);
    __syncthreads();
    for (int y = threadIdx.y; y < 32; y += 8)
        dst[(size_t)(bx + y) * 1024 + by + x] = t[x][y];
}

// ---------------- GEMM: C[m,n] = A[M,K] @ Bt[N,K]^T + bias(fp32) ------------
// A: fp32 if AF32 (X), else bf16 (ctx). Bt: bf16 (transposed weights).
// mode 0: FP32 out[m*1024+n]   (d_out is fp32 — the R12 discovery)
// mode 1: Q:  bf16 out[((b*16+h)*2048+s)*64+d] = v * 0.125
// mode 2: K:  bf16 out[((b*16+h)*2048+s)*64+d] = v
// mode 3: Vt: bf16 out[((b*16+h)*64+d)*2048+s] = v
template <bool AF32>
__global__ void gemm_bt(const void* __restrict__ A,
                        const ushort* __restrict__ Bt0, const ushort* __restrict__ Bt1,
                        const ushort* __restrict__ Bt2,
                        const float* __restrict__ bi0, const float* __restrict__ bi1,
                        const float* __restrict__ bi2,
                        void* __restrict__ o0, void* __restrict__ o1,
                        void* __restrict__ o2,
                        int mode0) {
    const int z = blockIdx.z;
    const ushort* Bt  = (z == 0) ? Bt0 : (z == 1) ? Bt1 : Bt2;
    const float* bia  = (z == 0) ? bi0 : (z == 1) ? bi1 : bi2;
    void* out         = (z == 0) ? o0  : (z == 1) ? o1  : o2;
    const int mode = mode0 + z;

    __shared__ __align__(16) ushort Asm[128 * 32];
    __shared__ __align__(16) ushort Bsm[128 * 32];

    const int t = threadIdx.x;
    const int lane = t & 63, w = t >> 6;
    const int wm = w >> 1, wn = w & 1;
    const int quad = lane >> 4, l16 = lane & 15;
    const int m0 = blockIdx.y * 128, n0 = blockIdx.x * 128;
    const int K = 1024;

    const f32x4 FZ = {0.f, 0.f, 0.f, 0.f};
    f32x4 acc[4][4];
#pragma unroll
    for (int i = 0; i < 4; i++)
#pragma unroll
        for (int j = 0; j < 4; j++) acc[i][j] = FZ;

    const int arow = t >> 2, ach = t & 3;
    const size_t abase = (size_t)(m0 + arow) * K + ach * 8;
    const ushort* Bp = Bt + (size_t)(n0 + arow) * K + ach * 8;

    for (int kt = 0; kt < K / 32; ++kt) {
        s16x8 av0 = load8<AF32>(A, abase + kt * 32);
        s16x8 av1 = load8<AF32>(A, abase + (size_t)64 * K + kt * 32);
        s16x8 bv0 = *(const s16x8*)(Bp + kt * 32);
        s16x8 bv1 = *(const s16x8*)(Bp + 64 * K + kt * 32);
        __syncthreads();
        *(s16x8*)((char*)Asm + t * 16)        = av0;
        *(s16x8*)((char*)Asm + 4096 + t * 16) = av1;
        *(s16x8*)((char*)Bsm + t * 16)        = bv0;
        *(s16x8*)((char*)Bsm + 4096 + t * 16) = bv1;
        __syncthreads();

        s16x8 a[4], b[4];
#pragma unroll
        for (int i = 0; i < 4; i++) {
            int row = wm * 64 + i * 16 + l16;
            a[i] = *(const s16x8*)((const char*)Asm + row * 64 + quad * 16);
        }
#pragma unroll
        for (int j = 0; j < 4; j++) {
            int row = wn * 64 + j * 16 + l16;
            b[j] = *(const s16x8*)((const char*)Bsm + row * 64 + quad * 16);
        }
#pragma unroll
        for (int i = 0; i < 4; i++)
#pragma unroll
            for (int j = 0; j < 4; j++)
                acc[i][j] = __builtin_amdgcn_mfma_f32_16x16x32_bf16(a[i], b[j], acc[i][j], 0, 0, 0);
    }

#pragma unroll
    for (int j = 0; j < 4; j++) {
        int n = n0 + wn * 64 + j * 16 + l16;
        float bv = bia[n];
#pragma unroll
        for (int i = 0; i < 4; i++) {
#pragma unroll
            for (int r = 0; r < 4; r++) {
                int m = m0 + wm * 64 + i * 16 + quad * 4 + r;
                float v = acc[i][j][r] + bv;
                if (mode == 0) {
                    ((float*)out)[(size_t)m * 1024 + n] = v;
                } else {
                    int b_ = m >> 11, s = m & 2047;
                    int h = n >> 6, d = n & 63;
                    if (mode == 1)
                        ((ushort*)out)[((size_t)(b_ * 16 + h) * 2048 + s) * 64 + d] = f2bf(v * 0.125f);
                    else if (mode == 2)
                        ((ushort*)out)[((size_t)(b_ * 16 + h) * 2048 + s) * 64 + d] = f2bf(v);
                    else
                        ((ushort*)out)[((size_t)(b_ * 16 + h) * 64 + d) * 2048 + s] = f2bf(v);
                }
            }
        }
    }
}

// ---------------- MFMA flash attention ----------------
// grid: (S/64, B*H), 256 threads. Q pre-scaled by 1/8. ctx verified correct
// (bit-identical to audited VALU attn across R4-R10 forensics).
__global__ void attn(const ushort* __restrict__ q_ws, const ushort* __restrict__ k_ws,
                     const ushort* __restrict__ vt_ws, ushort* __restrict__ ctx) {
    __shared__ __align__(16) ushort Qs[64][80];
    __shared__ __align__(16) ushort Ks[64][80];
    __shared__ __align__(16) ushort Vts[64][80];
    __shared__ __align__(16) ushort Ps[4][16][80];

    const int t = threadIdx.x, lane = t & 63, w = t >> 6;
    const int quad = lane >> 4, l16 = lane & 15;
    const int bh = blockIdx.y, q0 = blockIdx.x * 64;
    const ushort* Qg = q_ws + (size_t)bh * S_ * 64;
    const ushort* Kg = k_ws + (size_t)bh * S_ * 64;
    const ushort* Vg = vt_ws + (size_t)bh * 64 * S_;

    {
        int row = t >> 3, ch = t & 7;
        *(uint4*)&Qs[row][ch * 8]      = *(const uint4*)&Qg[(size_t)(q0 + row) * 64 + ch * 8];
        *(uint4*)&Qs[row + 32][ch * 8] = *(const uint4*)&Qg[(size_t)(q0 + row + 32) * 64 + ch * 8];
    }
    __syncthreads();
    s16x8 qa[2];
    qa[0] = *(const s16x8*)&Qs[w * 16 + l16][quad * 8];
    qa[1] = *(const s16x8*)&Qs[w * 16 + l16][32 + quad * 8];

    const f32x4 FZ = {0.f, 0.f, 0.f, 0.f};
    f32x4 o[4];
    float m_run[4], l_run[4];
#pragma unroll
    for (int i = 0; i < 4; i++) { o[i] = FZ; m_run[i] = -1e30f; l_run[i] = 0.f; }

    for (int kt = 0; kt < S_ / 64; ++kt) {
        __syncthreads();
        {
            int row = t >> 3, ch = t & 7;
            int k0 = kt * 64;
            *(uint4*)&Ks[row][ch * 8]       = *(const uint4*)&Kg[(size_t)(k0 + row) * 64 + ch * 8];
            *(uint4*)&Ks[row + 32][ch * 8]  = *(const uint4*)&Kg[(size_t)(k0 + row + 32) * 64 + ch * 8];
            *(uint4*)&Vts[row][ch * 8]      = *(const uint4*)&Vg[(size_t)row * S_ + k0 + ch * 8];
            *(uint4*)&Vts[row + 32][ch * 8] = *(const uint4*)&Vg[(size_t)(row + 32) * S_ + k0 + ch * 8];
        }
        __syncthreads();

        f32x4 c[4];
#pragma unroll
        for (int nch = 0; nch < 4; nch++) {
            c[nch] = FZ;
#pragma unroll
            for (int ks = 0; ks < 2; ks++) {
                s16x8 kb = *(const s16x8*)&Ks[nch * 16 + l16][ks * 32 + quad * 8];
                c[nch] = __builtin_amdgcn_mfma_f32_16x16x32_bf16(qa[ks], kb, c[nch], 0, 0, 0);
            }
        }

        float mnew[4], alpha[4];
#pragma unroll
        for (int r = 0; r < 4; r++) {
            float mx = fmaxf(fmaxf(c[0][r], c[1][r]), fmaxf(c[2][r], c[3][r]));
            mx = fmaxf(mx, __shfl_xor(mx, 1, 64));
            mx = fmaxf(mx, __shfl_xor(mx, 2, 64));
            mx = fmaxf(mx, __shfl_xor(mx, 4, 64));
            mx = fmaxf(mx, __shfl_xor(mx, 8, 64));
            mnew[r] = fmaxf(m_run[r], mx);
            alpha[r] = __expf(m_run[r] - mnew[r]);
            m_run[r] = mnew[r];
        }
        float rs[4] = {0.f, 0.f, 0.f, 0.f};
#pragma unroll
        for (int nch = 0; nch < 4; nch++) {
#pragma unroll
            for (int r = 0; r < 4; r++) {
                float p = __expf(c[nch][r] - mnew[r]);
                rs[r] += p;
                Ps[w][quad * 4 + r][nch * 16 + l16] = f2bf(p);
            }
        }
#pragma unroll
        for (int r = 0; r < 4; r++) {
            float s = rs[r];
            s += __shfl_xor(s, 1, 64);
            s += __shfl_xor(s, 2, 64);
            s += __shfl_xor(s, 4, 64);
            s += __shfl_xor(s, 8, 64);
            l_run[r] = l_run[r] * alpha[r] + s;
            o[0][r] *= alpha[r]; o[1][r] *= alpha[r];
            o[2][r] *= alpha[r]; o[3][r] *= alpha[r];
        }
        __syncthreads();
        s16x8 pa[2];
        pa[0] = *(const s16x8*)&Ps[w][l16][quad * 8];
        pa[1] = *(const s16x8*)&Ps[w][l16][32 + quad * 8];
#pragma unroll
        for (int dch = 0; dch < 4; dch++) {
#pragma unroll
            for (int ks = 0; ks < 2; ks++) {
                s16x8 vb = *(const s16x8*)&Vts[dch * 16 + l16][ks * 32 + quad * 8];
                o[dch] = __builtin_amdgcn_mfma_f32_16x16x32_bf16(pa[ks], vb, o[dch], 0, 0, 0);
            }
        }
    }

    int b_ = bh >> 4, h = bh & 15;
#pragma unroll
    for (int dch = 0; dch < 4; dch++) {
#pragma unroll
        for (int r = 0; r < 4; r++) {
            int s = q0 + w * 16 + quad * 4 + r;
            int col = h * 64 + dch * 16 + l16;
            ctx[((size_t)(b_ * 2048 + s)) * 1024 + col] = f2bf(o[dch][r] / l_run[r]);
        }
    }
}

extern "C" void kernel_launch(void* const* d_in, const int* in_sizes, int n_in,
                              void* d_out, int out_size, void* d_ws, size_t ws_size,
                              hipStream_t stream) {
    // Dict order; ALL inputs fp32; OUTPUT fp32 (R12-proven contract).
    const float* X  = (const float*)d_in[0];
    const float* Wq = (const float*)d_in[1];
    const float* bq = (const float*)d_in[2];
    const float* Wk = (const float*)d_in[3];
    const float* bk = (const float*)d_in[4];
    const float* Wv = (const float*)d_in[5];
    const float* bv = (const float*)d_in[6];
    const float* Wo = (const float*)d_in[7];
    const float* bo = (const float*)d_in[8];
    float* out = (float*)d_out;

    // ws (MiB): wtq@0(2) wtk@2(2) wtv@4(2) wto@6(2) qws@8(8) kws@16(8)
    // ctx@24(8) = 32 MiB (R12-proven size). V^T (8 MiB bf16) parks in d_out
    // (16 MiB fp32): dead before the final GEMM overwrites d_out.
    char* ws = (char*)d_ws;
    ushort* wtq  = (ushort*)(ws);
    ushort* wtk  = (ushort*)(ws + ((size_t)2 << 20));
    ushort* wtv  = (ushort*)(ws + ((size_t)4 << 20));
    ushort* wto  = (ushort*)(ws + ((size_t)6 << 20));
    ushort* qws  = (ushort*)(ws + ((size_t)8 << 20));
    ushort* kws  = (ushort*)(ws + ((size_t)16 << 20));
    ushort* ctx  = (ushort*)(ws + ((size_t)24 << 20));
    ushort* vtws = (ushort*)d_out;

    dim3 tb(32, 8), tg(32, 32);
    transpose_k<<<tg, tb, 0, stream>>>(Wq, wtq);
    transpose_k<<<tg, tb, 0, stream>>>(Wk, wtk);
    transpose_k<<<tg, tb, 0, stream>>>(Wv, wtv);
    transpose_k<<<tg, tb, 0, stream>>>(Wo, wto);

    // fused QKV projection (modes 1/2/3), A = X fp32
    gemm_bt<true><<<dim3(8, 32, 3), 256, 0, stream>>>(X, wtq, wtk, wtv, bq, bk, bv,
                                                      qws, kws, vtws, 1);

    attn<<<dim3(S_ / 64, 32), 256, 0, stream>>>(qws, kws, vtws, ctx);

    // output projection (mode 0), A = ctx bf16, OUT fp32
    gemm_bt<false><<<dim3(8, 32, 1), 256, 0, stream>>>(ctx, wto, wto, wto, bo, bo, bo,
                                                       out, out, out, 0);
}